// Round 1
// baseline (65.135 us; speedup 1.0000x reference)
//
#include <hip/hip_runtime.h>

#define NROWS 4096
#define NCOLS 4096
#define TPB   256

// LDS layout (floats):
//  [0 .. 6143]  : forward ping-pong E/O buffers; reused as rec R0[0..4095], R1[4096..6143] in backward
//  [6144..10239]: C — coeffs in final concat layout [d0(2048)|d1(1024)|...|d7(16)|approx(16)]
__global__ __launch_bounds__(TPB, 4) void despawn_kernel(
    const float* __restrict__ in, const float* __restrict__ wv,
    float* __restrict__ out_rec, float* __restrict__ out_coef)
{
    __shared__ float S[10240];
    float* C = S + 6144;
    const int row = blockIdx.x;
    const int tid = threadIdx.x;
    const float* rowIn = in + (size_t)row * NCOLS;

    // ---- load row, deinterleave into E (even samples) / O (odd samples) ----
    {
        float* E = S;
        float* O = S + 2048;
        for (int i = tid; i < 1024; i += TPB) {
            float4 v = reinterpret_cast<const float4*>(rowIn)[i];
            *reinterpret_cast<float2*>(E + 2 * i) = make_float2(v.x, v.z);
            *reinterpret_cast<float2*>(O + 2 * i) = make_float2(v.y, v.w);
        }
    }
    __syncthreads();

    // ---- forward: 8 levels ----
    {
        float* E  = S;            // current even half (len = part)
        float* O  = S + 2048;     // current odd half
        float* E2 = S + 4096;     // next even half (len = part/2)
        float* O2 = S + 5120;     // next odd half
        int part = 2048;          // outputs this level
        for (int lvl = 0; lvl < 8; ++lvl) {
            const float* w = wv + lvl * 16;
            float wl[16];
            #pragma unroll
            for (int q = 0; q < 16; ++q) wl[q] = w[q];
            float* det = C + (4096 - 2 * part);
            float* lastA = C + 4080;
            const bool last = (lvl == 7);
            const int pm = part - 1;
            for (int k = tid; k < part; k += TPB) {
                float d = 0.f, a = 0.f;
                #pragma unroll
                for (int t = 0; t < 8; ++t) {
                    int i = (k - t) & pm;          // signed AND == mod for pow2
                    float xe = E[i], xo = O[i];
                    d = fmaf(wl[2 * t], xe, d);
                    d = fmaf(wl[2 * t + 1], xo, d);
                    a = fmaf(wl[15 - 2 * t], xe, a);
                    a = fmaf(-wl[14 - 2 * t], xo, a);
                }
                det[k] = d;
                if (last) {
                    lastA[k] = a;                  // final approx, natural order
                } else {
                    float* dst = (k & 1) ? O2 : E2;  // write deinterleaved for next level
                    dst[k >> 1] = a;
                }
            }
            __syncthreads();
            float* t0 = E; E = E2; E2 = t0;
            float* t1 = O; O = O2; O2 = t1;
            part >>= 1;
        }
    }

    // ---- backward: 8 levels, rec ping-pongs between R1 (<=2048) and R0 (<=4096) ----
    {
        float* R0 = S;
        float* R1 = S + 4096;
        const float* A = C + 4080;   // deepest approx, len 16
        int md = 16;
        for (int lvl = 7; lvl >= 0; --lvl) {
            const float* w = wv + lvl * 16;
            float wl[16];
            #pragma unroll
            for (int q = 0; q < 16; ++q) wl[q] = w[q];
            const float* D = C + (4096 - 2 * md);
            float* out = (lvl & 1) ? R1 : R0;     // lvl0 (last) lands in R0[0..4095]
            const int mm = md - 1;
            for (int j = tid; j < md; j += TPB) {
                float r0 = 0.f, r1 = 0.f;
                #pragma unroll
                for (int t = 0; t < 8; ++t) {
                    int i = (j - t) & mm;
                    float dv = D[i], av = A[i];
                    r0 = fmaf(wl[15 - 2 * t], dv, r0);
                    r0 = fmaf(wl[2 * t],      av, r0);
                    r1 = fmaf(wl[14 - 2 * t], dv, r1);
                    r1 = fmaf(-wl[2 * t + 1], av, r1);
                }
                *reinterpret_cast<float2*>(out + 2 * j) = make_float2(r0, r1);
            }
            __syncthreads();
            A = out;
            md <<= 1;
        }
    }

    // ---- store rec (R0) and coeffs (C), coalesced float4 ----
    {
        const float* R0 = S;
        float* orow = out_rec  + (size_t)row * NCOLS;
        float* crow = out_coef + (size_t)row * NCOLS;
        for (int i = tid; i < 1024; i += TPB) {
            reinterpret_cast<float4*>(orow)[i] = reinterpret_cast<const float4*>(R0)[i];
            reinterpret_cast<float4*>(crow)[i] = reinterpret_cast<const float4*>(C)[i];
        }
    }
}

extern "C" void kernel_launch(void* const* d_in, const int* in_sizes, int n_in,
                              void* d_out, int out_size, void* d_ws, size_t ws_size,
                              hipStream_t stream) {
    (void)in_sizes; (void)n_in; (void)d_ws; (void)ws_size; (void)out_size;
    const float* in = (const float*)d_in[0];
    const float* wv = (const float*)d_in[1];
    float* out_rec  = (float*)d_out;
    float* out_coef = (float*)d_out + (size_t)NROWS * NCOLS;
    despawn_kernel<<<NROWS, TPB, 0, stream>>>(in, wv, out_rec, out_coef);
}

// Round 2
// 59.416 us; speedup vs baseline: 1.0963x; 1.0963x over previous
//
#include <hip/hip_runtime.h>

#define NROWS 4096
#define NCOLS 4096
#define TPB   256

// ---------- forward levels ----------

// P in {8,4}: part = P*TPB outputs, each thread computes P consecutive points.
template<int P>
__device__ __forceinline__ void fwd_big(const float* __restrict__ E, const float* __restrict__ O,
                                        float* __restrict__ det, float* __restrict__ E2,
                                        float* __restrict__ O2, const float* __restrict__ wl,
                                        int tid)
{
    const int part = P * TPB;
    const int pm4  = part / 4 - 1;
    const int k0   = tid * P;
    float xe[P + 8], xo[P + 8];
    const float4* E4 = (const float4*)E;
    const float4* O4 = (const float4*)O;
    const int b = ((k0 - 8) >> 2) & pm4;               // window start /4, modular
    #pragma unroll
    for (int j = 0; j < P / 4 + 2; ++j) {
        int idx = (b + j) & pm4;
        float4 v = E4[idx];
        float4 u = O4[idx];
        xe[4*j+0] = v.x; xe[4*j+1] = v.y; xe[4*j+2] = v.z; xe[4*j+3] = v.w;
        xo[4*j+0] = u.x; xo[4*j+1] = u.y; xo[4*j+2] = u.z; xo[4*j+3] = u.w;
    }
    float d[P], a[P];
    #pragma unroll
    for (int p = 0; p < P; ++p) {
        float dd = 0.f, aa = 0.f;
        #pragma unroll
        for (int t = 0; t < 8; ++t) {
            float e = xe[p - t + 8], o = xo[p - t + 8];
            dd = fmaf(wl[2*t],      e, dd);
            dd = fmaf(wl[2*t+1],    o, dd);
            aa = fmaf(wl[15-2*t],   e, aa);
            aa = fmaf(-wl[14-2*t],  o, aa);
        }
        d[p] = dd; a[p] = aa;
    }
    #pragma unroll
    for (int j = 0; j < P / 4; ++j)
        ((float4*)(det + k0))[j] = make_float4(d[4*j], d[4*j+1], d[4*j+2], d[4*j+3]);
    if (P == 8) {
        ((float4*)(E2 + k0/2))[0] = make_float4(a[0], a[2], a[4], a[6]);
        ((float4*)(O2 + k0/2))[0] = make_float4(a[1], a[3], a[5], a[7]);
    } else {
        ((float2*)(E2 + k0/2))[0] = make_float2(a[0], a[2]);
        ((float2*)(O2 + k0/2))[0] = make_float2(a[1], a[3]);
    }
}

// part = 512, P = 2, float2 window loads
__device__ __forceinline__ void fwd_mid(const float* __restrict__ E, const float* __restrict__ O,
                                        float* __restrict__ det, float* __restrict__ E2,
                                        float* __restrict__ O2, const float* __restrict__ wl,
                                        int tid)
{
    const int pm2 = 255;
    const int k0  = tid * 2;
    float xe[10], xo[10];
    const float2* Ev = (const float2*)E;
    const float2* Ov = (const float2*)O;
    const int b = ((k0 - 8) >> 1) & pm2;
    #pragma unroll
    for (int j = 0; j < 5; ++j) {
        int idx = (b + j) & pm2;
        float2 v = Ev[idx], u = Ov[idx];
        xe[2*j] = v.x; xe[2*j+1] = v.y;
        xo[2*j] = u.x; xo[2*j+1] = u.y;
    }
    float d[2], a[2];
    #pragma unroll
    for (int p = 0; p < 2; ++p) {
        float dd = 0.f, aa = 0.f;
        #pragma unroll
        for (int t = 0; t < 8; ++t) {
            float e = xe[p - t + 8], o = xo[p - t + 8];
            dd = fmaf(wl[2*t],     e, dd);
            dd = fmaf(wl[2*t+1],   o, dd);
            aa = fmaf(wl[15-2*t],  e, aa);
            aa = fmaf(-wl[14-2*t], o, aa);
        }
        d[p] = dd; a[p] = aa;
    }
    ((float2*)(det + k0))[0] = make_float2(d[0], d[1]);
    E2[k0 >> 1] = a[0];
    O2[k0 >> 1] = a[1];
}

// part <= 256, scalar
__device__ __forceinline__ void fwd_small(const float* __restrict__ E, const float* __restrict__ O,
                                          float* __restrict__ det, float* __restrict__ E2,
                                          float* __restrict__ O2, float* __restrict__ lastA,
                                          bool last, const float* __restrict__ wl,
                                          int tid, int part)
{
    const int pm = part - 1;
    if (tid < part) {
        const int k = tid;
        float dd = 0.f, aa = 0.f;
        #pragma unroll
        for (int t = 0; t < 8; ++t) {
            int i = (k - t) & pm;
            float e = E[i], o = O[i];
            dd = fmaf(wl[2*t],     e, dd);
            dd = fmaf(wl[2*t+1],   o, dd);
            aa = fmaf(wl[15-2*t],  e, aa);
            aa = fmaf(-wl[14-2*t], o, aa);
        }
        det[k] = dd;
        if (last) lastA[k] = aa;
        else { if (k & 1) O2[k >> 1] = aa; else E2[k >> 1] = aa; }
    }
}

// ---------- backward levels ----------

template<int P>
__device__ __forceinline__ void bwd_big(const float* __restrict__ D, const float* __restrict__ A,
                                        float* __restrict__ out, const float* __restrict__ wl,
                                        int tid)
{
    const int md  = P * TPB;
    const int pm4 = md / 4 - 1;
    const int j0  = tid * P;
    float xd[P + 8], xa[P + 8];
    const float4* D4 = (const float4*)D;
    const float4* A4 = (const float4*)A;
    const int b = ((j0 - 8) >> 2) & pm4;
    #pragma unroll
    for (int j = 0; j < P / 4 + 2; ++j) {
        int idx = (b + j) & pm4;
        float4 v = D4[idx];
        float4 u = A4[idx];
        xd[4*j+0] = v.x; xd[4*j+1] = v.y; xd[4*j+2] = v.z; xd[4*j+3] = v.w;
        xa[4*j+0] = u.x; xa[4*j+1] = u.y; xa[4*j+2] = u.z; xa[4*j+3] = u.w;
    }
    float r0[P], r1[P];
    #pragma unroll
    for (int p = 0; p < P; ++p) {
        float a0 = 0.f, a1 = 0.f;
        #pragma unroll
        for (int t = 0; t < 8; ++t) {
            float dv = xd[p - t + 8], av = xa[p - t + 8];
            a0 = fmaf(wl[15-2*t],  dv, a0);
            a0 = fmaf(wl[2*t],     av, a0);
            a1 = fmaf(wl[14-2*t],  dv, a1);
            a1 = fmaf(-wl[2*t+1],  av, a1);
        }
        r0[p] = a0; r1[p] = a1;
    }
    #pragma unroll
    for (int j = 0; j < P / 2; ++j)
        ((float4*)(out + 2*j0))[j] = make_float4(r0[2*j], r1[2*j], r0[2*j+1], r1[2*j+1]);
}

// md = 512, P = 2
__device__ __forceinline__ void bwd_mid(const float* __restrict__ D, const float* __restrict__ A,
                                        float* __restrict__ out, const float* __restrict__ wl,
                                        int tid)
{
    const int pm2 = 255;
    const int j0  = tid * 2;
    float xd[10], xa[10];
    const float2* Dv = (const float2*)D;
    const float2* Av = (const float2*)A;
    const int b = ((j0 - 8) >> 1) & pm2;
    #pragma unroll
    for (int j = 0; j < 5; ++j) {
        int idx = (b + j) & pm2;
        float2 v = Dv[idx], u = Av[idx];
        xd[2*j] = v.x; xd[2*j+1] = v.y;
        xa[2*j] = u.x; xa[2*j+1] = u.y;
    }
    float r0[2], r1[2];
    #pragma unroll
    for (int p = 0; p < 2; ++p) {
        float a0 = 0.f, a1 = 0.f;
        #pragma unroll
        for (int t = 0; t < 8; ++t) {
            float dv = xd[p - t + 8], av = xa[p - t + 8];
            a0 = fmaf(wl[15-2*t],  dv, a0);
            a0 = fmaf(wl[2*t],     av, a0);
            a1 = fmaf(wl[14-2*t],  dv, a1);
            a1 = fmaf(-wl[2*t+1],  av, a1);
        }
        r0[p] = a0; r1[p] = a1;
    }
    ((float4*)(out + 2*j0))[0] = make_float4(r0[0], r1[0], r0[1], r1[1]);
}

// md <= 256, scalar
__device__ __forceinline__ void bwd_small(const float* __restrict__ D, const float* __restrict__ A,
                                          float* __restrict__ out, const float* __restrict__ wl,
                                          int tid, int md)
{
    const int mm = md - 1;
    if (tid < md) {
        const int j = tid;
        float a0 = 0.f, a1 = 0.f;
        #pragma unroll
        for (int t = 0; t < 8; ++t) {
            int i = (j - t) & mm;
            float dv = D[i], av = A[i];
            a0 = fmaf(wl[15-2*t],  dv, a0);
            a0 = fmaf(wl[2*t],     av, a0);
            a1 = fmaf(wl[14-2*t],  dv, a1);
            a1 = fmaf(-wl[2*t+1],  av, a1);
        }
        ((float2*)(out + 2*j))[0] = make_float2(a0, a1);
    }
}

// ---------- kernel ----------
// LDS layout (floats):
//  [0..6143]    ping-pong E/O (fwd) -> R0[0..4095], R1[4096..6143] (bwd)
//  [6144..10239] C: coeffs in concat layout [d0(2048)|d1(1024)|...|d7(16)|a7(16)]
__global__ __launch_bounds__(TPB, 4) void despawn_kernel(
    const float* __restrict__ in, const float* __restrict__ wv,
    float* __restrict__ out_rec, float* __restrict__ out_coef)
{
    __shared__ float S[10240];
    float* C = S + 6144;
    const int row = blockIdx.x;
    const int tid = threadIdx.x;
    const float* rowIn = in + (size_t)row * NCOLS;

    // load + deinterleave
    {
        float* E = S;
        float* O = S + 2048;
        for (int i = tid; i < 1024; i += TPB) {
            float4 v = reinterpret_cast<const float4*>(rowIn)[i];
            *reinterpret_cast<float2*>(E + 2 * i) = make_float2(v.x, v.z);
            *reinterpret_cast<float2*>(O + 2 * i) = make_float2(v.y, v.w);
        }
    }
    __syncthreads();

    // ---- forward ----
    {
        float* E  = S;
        float* O  = S + 2048;
        float* E2 = S + 4096;
        float* O2 = S + 5120;
        float* t;
        fwd_big<8>(E, O, C + 0, E2, O2, wv + 0, tid);            // part 2048, det@0
        __syncthreads(); t=E; E=E2; E2=t; t=O; O=O2; O2=t;
        fwd_big<4>(E, O, C + 2048, E2, O2, wv + 16, tid);        // part 1024, det@2048
        __syncthreads(); t=E; E=E2; E2=t; t=O; O=O2; O2=t;
        fwd_mid(E, O, C + 3072, E2, O2, wv + 32, tid);           // part 512,  det@3072
        __syncthreads(); t=E; E=E2; E2=t; t=O; O=O2; O2=t;
        int part = 256;
        for (int lvl = 3; lvl < 8; ++lvl, part >>= 1) {
            fwd_small(E, O, C + (4096 - 2 * part), E2, O2, C + 4080,
                      lvl == 7, wv + 16 * lvl, tid, part);
            __syncthreads(); t=E; E=E2; E2=t; t=O; O=O2; O2=t;
        }
    }

    // ---- backward ----
    {
        float* R0 = S;
        float* R1 = S + 4096;
        const float* A = C + 4080;
        int md = 16;
        for (int lvl = 7; lvl >= 3; --lvl, md <<= 1) {
            float* out = (lvl & 1) ? R1 : R0;
            bwd_small(C + (4096 - 2 * md), A, out, wv + 16 * lvl, tid, md);
            __syncthreads();
            A = out;
        }
        bwd_mid(C + 3072, A, R0, wv + 32, tid);                  // md 512 -> R0 (len 1024)
        __syncthreads(); A = R0;
        bwd_big<4>(C + 2048, A, R1, wv + 16, tid);               // md 1024 -> R1 (len 2048)
        __syncthreads(); A = R1;
        bwd_big<8>(C + 0, A, R0, wv + 0, tid);                   // md 2048 -> R0 (len 4096)
        __syncthreads();
    }

    // ---- store ----
    {
        const float* R0 = S;
        float* orow = out_rec  + (size_t)row * NCOLS;
        float* crow = out_coef + (size_t)row * NCOLS;
        for (int i = tid; i < 1024; i += TPB) {
            reinterpret_cast<float4*>(orow)[i] = reinterpret_cast<const float4*>(R0)[i];
            reinterpret_cast<float4*>(crow)[i] = reinterpret_cast<const float4*>(C)[i];
        }
    }
}

extern "C" void kernel_launch(void* const* d_in, const int* in_sizes, int n_in,
                              void* d_out, int out_size, void* d_ws, size_t ws_size,
                              hipStream_t stream) {
    (void)in_sizes; (void)n_in; (void)d_ws; (void)ws_size; (void)out_size;
    const float* in = (const float*)d_in[0];
    const float* wv = (const float*)d_in[1];
    float* out_rec  = (float*)d_out;
    float* out_coef = (float*)d_out + (size_t)NROWS * NCOLS;
    despawn_kernel<<<NROWS, TPB, 0, stream>>>(in, wv, out_rec, out_coef);
}

// Round 3
// 52.414 us; speedup vs baseline: 1.2427x; 1.1336x over previous
//
#include <hip/hip_runtime.h>

#define NROWS 4096
#define NCOLS 4096
#define TPB   256

// Global coeff row layout (floats):
// [det0 2048 | det1 1024 | det2 512 | det3 256 | det4 128 | det5 64 | det6 32 | det7 16 | a7 16]
// LDS: P0[2048] ping, P1[1024] pong, Csm[512] = mirror of global offsets 3584..4095.

__global__ __launch_bounds__(TPB, 6) void despawn_kernel(
    const float* __restrict__ in, const float* __restrict__ wv,
    float* __restrict__ out_rec, float* __restrict__ out_coef)
{
    __shared__ float P0[2048];
    __shared__ float P1[1024];
    __shared__ float Csm[512];

    const int tid = threadIdx.x;
    const int row = blockIdx.x;
    const float* rowIn = in + (size_t)row * NCOLS;
    float* crow = out_coef + (size_t)row * NCOLS;
    float* rrow = out_rec  + (size_t)row * NCOLS;

    float wl[16];

    // ================= forward level 0: global x -> det0(global), E1|O1 -> P0 =================
    {
        #pragma unroll
        for (int q = 0; q < 16; ++q) wl[q] = wv[q];
        float xw[32];
        const float4* X4 = (const float4*)rowIn;           // 1024 blocks
        #pragma unroll
        for (int j = 0; j < 8; ++j) {
            int q = (4 * tid - 4 + j) & 1023;
            float4 v = X4[q];
            xw[4*j+0]=v.x; xw[4*j+1]=v.y; xw[4*j+2]=v.z; xw[4*j+3]=v.w;
        }
        // xw[i] = x[(16t-16+i) mod 4096]; E[k-s]=xw[16+2p-2s], O[k-s]=xw[17+2p-2s]
        float d[8], a[8];
        #pragma unroll
        for (int p = 0; p < 8; ++p) {
            float dd = 0.f, aa = 0.f;
            #pragma unroll
            for (int t = 0; t < 8; ++t) {
                float e = xw[16 + 2*p - 2*t];
                float o = xw[17 + 2*p - 2*t];
                dd = fmaf(wl[2*t],     e, dd);
                dd = fmaf(wl[2*t+1],   o, dd);
                aa = fmaf(wl[15-2*t],  e, aa);
                aa = fmaf(-wl[14-2*t], o, aa);
            }
            d[p] = dd; a[p] = aa;
        }
        const int k0 = tid * 8;
        ((float4*)(crow + k0))[0] = make_float4(d[0],d[1],d[2],d[3]);
        ((float4*)(crow + k0))[1] = make_float4(d[4],d[5],d[6],d[7]);
        *(float4*)(P0 + (k0>>1))        = make_float4(a[0],a[2],a[4],a[6]);  // E1
        *(float4*)(P0 + 1024 + (k0>>1)) = make_float4(a[1],a[3],a[5],a[7]);  // O1
    }
    __syncthreads();

    // ================= forward level 1: P0 -> det1(global), E2|O2 -> P1 =================
    {
        #pragma unroll
        for (int q = 0; q < 16; ++q) wl[q] = wv[16 + q];
        const float4* E4 = (const float4*)P0;              // 256 blocks
        const float4* O4 = (const float4*)(P0 + 1024);
        float xe[12], xo[12];
        #pragma unroll
        for (int j = 0; j < 3; ++j) {
            int idx = (tid - 2 + j) & 255;
            float4 v = E4[idx], u = O4[idx];
            xe[4*j]=v.x; xe[4*j+1]=v.y; xe[4*j+2]=v.z; xe[4*j+3]=v.w;
            xo[4*j]=u.x; xo[4*j+1]=u.y; xo[4*j+2]=u.z; xo[4*j+3]=u.w;
        }
        float d[4], a[4];
        #pragma unroll
        for (int p = 0; p < 4; ++p) {
            float dd = 0.f, aa = 0.f;
            #pragma unroll
            for (int t = 0; t < 8; ++t) {
                float e = xe[8+p-t], o = xo[8+p-t];
                dd = fmaf(wl[2*t],     e, dd);
                dd = fmaf(wl[2*t+1],   o, dd);
                aa = fmaf(wl[15-2*t],  e, aa);
                aa = fmaf(-wl[14-2*t], o, aa);
            }
            d[p] = dd; a[p] = aa;
        }
        const int k0 = tid * 4;
        *(float4*)(crow + 2048 + k0) = make_float4(d[0],d[1],d[2],d[3]);
        *(float2*)(P1 + (k0>>1))       = make_float2(a[0], a[2]);  // E2
        *(float2*)(P1 + 512 + (k0>>1)) = make_float2(a[1], a[3]);  // O2
    }
    __syncthreads();

    // ================= forward level 2: P1 -> det2(global), E3|O3 -> P0 =================
    {
        #pragma unroll
        for (int q = 0; q < 16; ++q) wl[q] = wv[32 + q];
        const float2* Ev = (const float2*)P1;              // 256 blocks
        const float2* Ov = (const float2*)(P1 + 512);
        float xe[10], xo[10];
        #pragma unroll
        for (int j = 0; j < 5; ++j) {
            int idx = (tid - 4 + j) & 255;
            float2 v = Ev[idx], u = Ov[idx];
            xe[2*j]=v.x; xe[2*j+1]=v.y;
            xo[2*j]=u.x; xo[2*j+1]=u.y;
        }
        float d[2], a[2];
        #pragma unroll
        for (int p = 0; p < 2; ++p) {
            float dd = 0.f, aa = 0.f;
            #pragma unroll
            for (int t = 0; t < 8; ++t) {
                float e = xe[8+p-t], o = xo[8+p-t];
                dd = fmaf(wl[2*t],     e, dd);
                dd = fmaf(wl[2*t+1],   o, dd);
                aa = fmaf(wl[15-2*t],  e, aa);
                aa = fmaf(-wl[14-2*t], o, aa);
            }
            d[p] = dd; a[p] = aa;
        }
        const int k0 = tid * 2;
        *(float2*)(crow + 3072 + k0) = make_float2(d[0], d[1]);
        P0[tid]       = a[0];   // E3 (256)
        P0[256 + tid] = a[1];   // O3
    }
    __syncthreads();

    // ================= forward levels 3..7: LDS ping-pong, det -> Csm + global =================
    {
        float* bin  = P0;
        float* bout = P1;
        int part = 256;      // outputs at this level (= E/O array length)
        int coff = 3584;     // det offset in crow
        for (int lvl = 3; lvl < 8; ++lvl) {
            #pragma unroll
            for (int q = 0; q < 16; ++q) wl[q] = wv[16*lvl + q];
            const int nth = part >> 2;
            if (tid < nth) {
                const int pm = nth - 1;
                const float4* E4 = (const float4*)bin;
                const float4* O4 = (const float4*)(bin + part);
                float xe[12], xo[12];
                #pragma unroll
                for (int j = 0; j < 3; ++j) {
                    int idx = (tid - 2 + j) & pm;
                    float4 v = E4[idx], u = O4[idx];
                    xe[4*j]=v.x; xe[4*j+1]=v.y; xe[4*j+2]=v.z; xe[4*j+3]=v.w;
                    xo[4*j]=u.x; xo[4*j+1]=u.y; xo[4*j+2]=u.z; xo[4*j+3]=u.w;
                }
                float d[4], a[4];
                #pragma unroll
                for (int p = 0; p < 4; ++p) {
                    float dd = 0.f, aa = 0.f;
                    #pragma unroll
                    for (int t = 0; t < 8; ++t) {
                        float e = xe[8+p-t], o = xo[8+p-t];
                        dd = fmaf(wl[2*t],     e, dd);
                        dd = fmaf(wl[2*t+1],   o, dd);
                        aa = fmaf(wl[15-2*t],  e, aa);
                        aa = fmaf(-wl[14-2*t], o, aa);
                    }
                    d[p] = dd; a[p] = aa;
                }
                const int k0 = tid * 4;
                float4 dv = make_float4(d[0],d[1],d[2],d[3]);
                *(float4*)(crow + coff + k0)        = dv;
                *(float4*)(Csm + (coff - 3584) + k0) = dv;
                if (lvl == 7) {
                    float4 av = make_float4(a[0],a[1],a[2],a[3]);
                    *(float4*)(crow + 4080 + k0) = av;
                    *(float4*)(Csm + 496 + k0)   = av;
                } else {
                    *(float2*)(bout + (k0>>1))              = make_float2(a[0], a[2]);
                    *(float2*)(bout + (part>>1) + (k0>>1))  = make_float2(a[1], a[3]);
                }
            }
            __syncthreads();
            float* tmp = bin; bin = bout; bout = tmp;
            coff += part;
            part >>= 1;
        }
    }

    // ================= backward levels 7..3: D,A from LDS, out -> LDS ping-pong =================
    const float* A = Csm + 496;   // a7
    {
        float* bo   = P0;
        float* balt = P1;
        int md = 16;
        int doffL = 480;          // det7 in Csm
        for (int lvl = 7; lvl >= 3; --lvl) {
            #pragma unroll
            for (int q = 0; q < 16; ++q) wl[q] = wv[16*lvl + q];
            const int nth = md >> 2;
            if (tid < nth) {
                const int pm = nth - 1;
                const float4* D4 = (const float4*)(Csm + doffL);
                const float4* A4 = (const float4*)A;
                float xd[12], xa[12];
                #pragma unroll
                for (int j = 0; j < 3; ++j) {
                    int idx = (tid - 2 + j) & pm;
                    float4 v = D4[idx], u = A4[idx];
                    xd[4*j]=v.x; xd[4*j+1]=v.y; xd[4*j+2]=v.z; xd[4*j+3]=v.w;
                    xa[4*j]=u.x; xa[4*j+1]=u.y; xa[4*j+2]=u.z; xa[4*j+3]=u.w;
                }
                float r0[4], r1[4];
                #pragma unroll
                for (int p = 0; p < 4; ++p) {
                    float a0 = 0.f, a1 = 0.f;
                    #pragma unroll
                    for (int t = 0; t < 8; ++t) {
                        float dv = xd[8+p-t], av = xa[8+p-t];
                        a0 = fmaf(wl[15-2*t], dv, a0);
                        a0 = fmaf(wl[2*t],    av, a0);
                        a1 = fmaf(wl[14-2*t], dv, a1);
                        a1 = fmaf(-wl[2*t+1], av, a1);
                    }
                    r0[p] = a0; r1[p] = a1;
                }
                const int j0 = tid * 4;
                ((float4*)(bo + 2*j0))[0] = make_float4(r0[0],r1[0],r0[1],r1[1]);
                ((float4*)(bo + 2*j0))[1] = make_float4(r0[2],r1[2],r0[3],r1[3]);
            }
            __syncthreads();
            A = bo;
            float* tmp = bo; bo = balt; balt = tmp;
            md <<= 1;
            doffL -= md;
        }
    }
    // now A = P0 (512 floats), md = 512

    // ================= backward level 2: D=global det2, A=P0 -> P1 (1024) =================
    {
        #pragma unroll
        for (int q = 0; q < 16; ++q) wl[q] = wv[32 + q];
        const float2* Dg = (const float2*)(crow + 3072);   // 256 blocks
        const float2* A2 = (const float2*)A;               // 256 blocks
        float xd[10], xa[10];
        #pragma unroll
        for (int j = 0; j < 5; ++j) {
            int idx = (tid - 4 + j) & 255;
            float2 v = Dg[idx], u = A2[idx];
            xd[2*j]=v.x; xd[2*j+1]=v.y;
            xa[2*j]=u.x; xa[2*j+1]=u.y;
        }
        float r0[2], r1[2];
        #pragma unroll
        for (int p = 0; p < 2; ++p) {
            float a0 = 0.f, a1 = 0.f;
            #pragma unroll
            for (int t = 0; t < 8; ++t) {
                float dv = xd[8+p-t], av = xa[8+p-t];
                a0 = fmaf(wl[15-2*t], dv, a0);
                a0 = fmaf(wl[2*t],    av, a0);
                a1 = fmaf(wl[14-2*t], dv, a1);
                a1 = fmaf(-wl[2*t+1], av, a1);
            }
            r0[p] = a0; r1[p] = a1;
        }
        const int j0 = tid * 2;
        *(float4*)(P1 + 2*j0) = make_float4(r0[0],r1[0],r0[1],r1[1]);
    }
    __syncthreads();

    // ================= backward level 1: D=global det1, A=P1 -> P0 (2048) =================
    {
        #pragma unroll
        for (int q = 0; q < 16; ++q) wl[q] = wv[16 + q];
        const float4* Dg = (const float4*)(crow + 2048);   // 256 blocks
        const float4* A4 = (const float4*)P1;              // 256 blocks
        float xd[12], xa[12];
        #pragma unroll
        for (int j = 0; j < 3; ++j) {
            int idx = (tid - 2 + j) & 255;
            float4 v = Dg[idx], u = A4[idx];
            xd[4*j]=v.x; xd[4*j+1]=v.y; xd[4*j+2]=v.z; xd[4*j+3]=v.w;
            xa[4*j]=u.x; xa[4*j+1]=u.y; xa[4*j+2]=u.z; xa[4*j+3]=u.w;
        }
        float r0[4], r1[4];
        #pragma unroll
        for (int p = 0; p < 4; ++p) {
            float a0 = 0.f, a1 = 0.f;
            #pragma unroll
            for (int t = 0; t < 8; ++t) {
                float dv = xd[8+p-t], av = xa[8+p-t];
                a0 = fmaf(wl[15-2*t], dv, a0);
                a0 = fmaf(wl[2*t],    av, a0);
                a1 = fmaf(wl[14-2*t], dv, a1);
                a1 = fmaf(-wl[2*t+1], av, a1);
            }
            r0[p] = a0; r1[p] = a1;
        }
        const int j0 = tid * 4;
        ((float4*)(P0 + 2*j0))[0] = make_float4(r0[0],r1[0],r0[1],r1[1]);
        ((float4*)(P0 + 2*j0))[1] = make_float4(r0[2],r1[2],r0[3],r1[3]);
    }
    __syncthreads();

    // ================= backward level 0: D=global det0, A=P0 -> rec (global) =================
    {
        #pragma unroll
        for (int q = 0; q < 16; ++q) wl[q] = wv[q];
        const float4* Dg = (const float4*)crow;            // 512 blocks
        const float4* A4 = (const float4*)P0;              // 512 blocks
        float xd[16], xa[16];
        #pragma unroll
        for (int j = 0; j < 4; ++j) {
            int idx = (2*tid - 2 + j) & 511;
            float4 v = Dg[idx], u = A4[idx];
            xd[4*j]=v.x; xd[4*j+1]=v.y; xd[4*j+2]=v.z; xd[4*j+3]=v.w;
            xa[4*j]=u.x; xa[4*j+1]=u.y; xa[4*j+2]=u.z; xa[4*j+3]=u.w;
        }
        float r0[8], r1[8];
        #pragma unroll
        for (int p = 0; p < 8; ++p) {
            float a0 = 0.f, a1 = 0.f;
            #pragma unroll
            for (int t = 0; t < 8; ++t) {
                float dv = xd[8+p-t], av = xa[8+p-t];
                a0 = fmaf(wl[15-2*t], dv, a0);
                a0 = fmaf(wl[2*t],    av, a0);
                a1 = fmaf(wl[14-2*t], dv, a1);
                a1 = fmaf(-wl[2*t+1], av, a1);
            }
            r0[p] = a0; r1[p] = a1;
        }
        const int j0 = tid * 8;
        float4* R = (float4*)(rrow + 2*j0);
        R[0] = make_float4(r0[0],r1[0],r0[1],r1[1]);
        R[1] = make_float4(r0[2],r1[2],r0[3],r1[3]);
        R[2] = make_float4(r0[4],r1[4],r0[5],r1[5]);
        R[3] = make_float4(r0[6],r1[6],r0[7],r1[7]);
    }
}

extern "C" void kernel_launch(void* const* d_in, const int* in_sizes, int n_in,
                              void* d_out, int out_size, void* d_ws, size_t ws_size,
                              hipStream_t stream) {
    (void)in_sizes; (void)n_in; (void)d_ws; (void)ws_size; (void)out_size;
    const float* in = (const float*)d_in[0];
    const float* wv = (const float*)d_in[1];
    float* out_rec  = (float*)d_out;
    float* out_coef = (float*)d_out + (size_t)NROWS * NCOLS;
    despawn_kernel<<<NROWS, TPB, 0, stream>>>(in, wv, out_rec, out_coef);
}